// Round 1
// baseline (1722.384 us; speedup 1.0000x reference)
//
#include <hip/hip_runtime.h>

#define N_NODES 100000
#define N_EDGES 600000
#define EPS_BN 1e-5f
#define EPS_NORM 1e-12f

// ---------------------------------------------------------------------------
// Degree count (float, exact for small ints) + reciprocal of max(cnt,1)
// ---------------------------------------------------------------------------
__global__ void k_count(const int* __restrict__ dst, float* __restrict__ cnt, int E) {
    int e = blockIdx.x * blockDim.x + threadIdx.x;
    if (e < E) atomicAdd(&cnt[dst[e]], 1.0f);
}

__global__ void k_inv(float* __restrict__ cnt, int n) {
    int i = blockIdx.x * blockDim.x + threadIdx.x;
    if (i < n) cnt[i] = 1.0f / fmaxf(cnt[i], 1.0f);
}

// ---------------------------------------------------------------------------
// Scatter-add: thread per (edge, channel). Consecutive threads hit
// consecutive channels -> atomics coalesce within a cache line.
// ---------------------------------------------------------------------------
template <int D>
__global__ void k_scatter(const float* __restrict__ h, const int* __restrict__ src,
                          const int* __restrict__ dst, float* __restrict__ agg, int E) {
    int tid = blockIdx.x * blockDim.x + threadIdx.x;
    if (tid >= E * D) return;
    int e = tid / D;
    int d = tid - e * D;
    atomicAdd(&agg[(size_t)dst[e] * D + d], h[(size_t)src[e] * D + d]);
}

// ---------------------------------------------------------------------------
// Fused linear + BN(+ReLU): out[node,c] = bn( (agg[node]*inv) @ Wl + h @ Wr + b )
// Thread per (node, out-channel). Weight reads coalesced across c; node-row
// reads are wave-broadcast (same address) and L1-resident.
// ---------------------------------------------------------------------------
template <int DIN, int DOUT, bool RELU>
__global__ void k_linear(const float* __restrict__ h, const float* __restrict__ agg,
                         const float* __restrict__ inv_cnt,
                         const float* __restrict__ Wl, const float* __restrict__ Wr,
                         const float* __restrict__ bias,
                         const float* __restrict__ bn_g, const float* __restrict__ bn_b,
                         const float* __restrict__ bn_m, const float* __restrict__ bn_v,
                         float* __restrict__ out, int n) {
    int tid = blockIdx.x * blockDim.x + threadIdx.x;
    int node = tid / DOUT;
    int c = tid - node * DOUT;
    if (node >= n) return;

    float inv = inv_cnt[node];
    const float* hr = h + (size_t)node * DIN;
    const float* ar = agg + (size_t)node * DIN;

    float acc = bias[c];
#pragma unroll
    for (int k = 0; k < DIN; ++k) {
        acc += (ar[k] * inv) * Wl[k * DOUT + c] + hr[k] * Wr[k * DOUT + c];
    }
    float o = (acc - bn_m[c]) * rsqrtf(bn_v[c] + EPS_BN) * bn_g[c] + bn_b[c];
    if (RELU) o = fmaxf(o, 0.0f);
    out[(size_t)node * DOUT + c] = o;
}

// ---------------------------------------------------------------------------
// L2-normalize (in place, d_out emb region) + logits = emb @ Wc + bc.
// One 64-lane wave per node; each lane owns channels {lane, lane+64}.
// ---------------------------------------------------------------------------
__global__ void k_norm_logits(float* __restrict__ emb, float* __restrict__ logits,
                              const float* __restrict__ Wc, const float* __restrict__ bc,
                              int n) {
    int gtid = blockIdx.x * blockDim.x + threadIdx.x;
    int node = gtid >> 6;
    int lane = threadIdx.x & 63;
    if (node >= n) return;

    float* row = emb + (size_t)node * 128;
    float a = row[lane];
    float b = row[lane + 64];

    float ss = a * a + b * b;
#pragma unroll
    for (int off = 32; off; off >>= 1) ss += __shfl_down(ss, off, 64);
    ss = __shfl(ss, 0, 64);

    float inv = 1.0f / fmaxf(sqrtf(ss), EPS_NORM);
    a *= inv;
    b *= inv;
    row[lane] = a;
    row[lane + 64] = b;

    float l0 = a * Wc[lane * 2 + 0] + b * Wc[(lane + 64) * 2 + 0];
    float l1 = a * Wc[lane * 2 + 1] + b * Wc[(lane + 64) * 2 + 1];
#pragma unroll
    for (int off = 32; off; off >>= 1) {
        l0 += __shfl_down(l0, off, 64);
        l1 += __shfl_down(l1, off, 64);
    }
    if (lane == 0) {
        logits[(size_t)node * 2 + 0] = l0 + bc[0];
        logits[(size_t)node * 2 + 1] = l1 + bc[1];
    }
}

// ---------------------------------------------------------------------------
extern "C" void kernel_launch(void* const* d_in, const int* in_sizes, int n_in,
                              void* d_out, int out_size, void* d_ws, size_t ws_size,
                              hipStream_t stream) {
    const float* x    = (const float*)d_in[0];
    const int*   ei   = (const int*)d_in[1];
    const int*   src  = ei;            // edge_index[0]
    const int*   dstp = ei + N_EDGES;  // edge_index[1]

    const float* W1l = (const float*)d_in[2];
    const float* W1r = (const float*)d_in[3];
    const float* b1  = (const float*)d_in[4];
    const float* g1  = (const float*)d_in[5];
    const float* bb1 = (const float*)d_in[6];
    const float* m1  = (const float*)d_in[7];
    const float* v1  = (const float*)d_in[8];

    const float* W2l = (const float*)d_in[9];
    const float* W2r = (const float*)d_in[10];
    const float* b2  = (const float*)d_in[11];
    const float* g2  = (const float*)d_in[12];
    const float* bb2 = (const float*)d_in[13];
    const float* m2  = (const float*)d_in[14];
    const float* v2  = (const float*)d_in[15];

    const float* W3l = (const float*)d_in[16];
    const float* W3r = (const float*)d_in[17];
    const float* b3  = (const float*)d_in[18];
    const float* g3  = (const float*)d_in[19];
    const float* bb3 = (const float*)d_in[20];
    const float* m3  = (const float*)d_in[21];
    const float* v3  = (const float*)d_in[22];

    const float* Wc = (const float*)d_in[23];
    const float* bc = (const float*)d_in[24];

    // workspace layout (floats)
    float* ws  = (float*)d_ws;
    float* cnt = ws;                                  // N          (becomes inv_cnt)
    float* agg = cnt + N_NODES;                       // N*128
    float* h1  = agg + (size_t)N_NODES * 128;         // N*64
    float* h2  = h1 + (size_t)N_NODES * 64;           // N*128

    float* emb    = (float*)d_out;                    // N*128
    float* logits = emb + (size_t)N_NODES * 128;      // N*2

    const int B = 256;

    // degree counts (reused for all 3 layers)
    hipMemsetAsync(cnt, 0, N_NODES * sizeof(float), stream);
    k_count<<<(N_EDGES + B - 1) / B, B, 0, stream>>>(dstp, cnt, N_EDGES);
    k_inv<<<(N_NODES + B - 1) / B, B, 0, stream>>>(cnt, N_NODES);

    // ---- layer 1: 10 -> 64, ReLU ----
    hipMemsetAsync(agg, 0, (size_t)N_NODES * 10 * sizeof(float), stream);
    k_scatter<10><<<(N_EDGES * 10 + B - 1) / B, B, 0, stream>>>(x, src, dstp, agg, N_EDGES);
    k_linear<10, 64, true><<<((size_t)N_NODES * 64 + B - 1) / B, B, 0, stream>>>(
        x, agg, cnt, W1l, W1r, b1, g1, bb1, m1, v1, h1, N_NODES);

    // ---- layer 2: 64 -> 128, ReLU ----
    hipMemsetAsync(agg, 0, (size_t)N_NODES * 64 * sizeof(float), stream);
    k_scatter<64><<<(N_EDGES * 64 + B - 1) / B, B, 0, stream>>>(h1, src, dstp, agg, N_EDGES);
    k_linear<64, 128, true><<<((size_t)N_NODES * 128 + B - 1) / B, B, 0, stream>>>(
        h1, agg, cnt, W2l, W2r, b2, g2, bb2, m2, v2, h2, N_NODES);

    // ---- layer 3: 128 -> 128, no ReLU, straight into d_out emb region ----
    hipMemsetAsync(agg, 0, (size_t)N_NODES * 128 * sizeof(float), stream);
    k_scatter<128><<<((size_t)N_EDGES * 128 + B - 1) / B, B, 0, stream>>>(h2, src, dstp, agg, N_EDGES);
    k_linear<128, 128, false><<<((size_t)N_NODES * 128 + B - 1) / B, B, 0, stream>>>(
        h2, agg, cnt, W3l, W3r, b3, g3, bb3, m3, v3, emb, N_NODES);

    // ---- normalize + logits ----
    k_norm_logits<<<((size_t)N_NODES * 64 + B - 1) / B, B, 0, stream>>>(emb, logits, Wc, bc, N_NODES);
}